// Round 10
// baseline (2676.152 us; speedup 1.0000x reference)
//
#include <hip/hip_runtime.h>
#include <cstdint>
#include <cstddef>

#define DM 2048
#define DFF_ 8192
#define NR 4096        // B*S rows
#define SEQ_ 2048
#define KVB 64
#define QK_SCALE 0.2973017787506803f
#define QK_SCALE_L2E 0.42891582f   // QK_SCALE * log2(e): Q pre-scaled for exp2 softmax

typedef unsigned short u16;
typedef __attribute__((ext_vector_type(8))) __bf16 bf16x8;
typedef __attribute__((ext_vector_type(8))) unsigned short us8;
typedef __attribute__((ext_vector_type(4))) unsigned short us4;
typedef __attribute__((ext_vector_type(4))) float f32x4;

static __device__ __forceinline__ u16 f2bf(float f) {
  union { float f; unsigned u; } x; x.f = f;
  unsigned r = x.u + 0x7fffu + ((x.u >> 16) & 1u);
  return (u16)(r >> 16);
}

#define GLL(srcp, dstp) __builtin_amdgcn_global_load_lds( \
    (const __attribute__((address_space(1))) void*)(srcp), \
    (__attribute__((address_space(3))) void*)(dstp), 16, 0, 0)
#define BAR() __builtin_amdgcn_s_barrier()
#define SB0() __builtin_amdgcn_sched_barrier(0)
#define LGKM0() do { asm volatile("s_waitcnt lgkmcnt(0)" ::: "memory"); SB0(); } while (0)
#define VMCN(n)  do { asm volatile("s_waitcnt vmcnt(" #n ")" ::: "memory");  SB0(); } while (0)

// ---------------- fp32 -> bf16 conversion (vectorized, grid-stride) ----------
__global__ __launch_bounds__(256) void cvt_bf16_k(const float* __restrict__ in,
                                                  u16* __restrict__ out, int n4) {
  int i = blockIdx.x * 256 + threadIdx.x;
  int st = gridDim.x * 256;
  for (; i < n4; i += st) {
    float4 v = ((const float4*)in)[i];
    us4 o;
    o.x = f2bf(v.x); o.y = f2bf(v.y); o.z = f2bf(v.z); o.w = f2bf(v.w);
    ((us4*)out)[i] = o;
  }
}

__global__ __launch_bounds__(256) void concat3_k(const float* a, const float* b,
                                                 const float* c, float* o) {
  int i = blockIdx.x * 256 + threadIdx.x;
  if (i < DM) { o[i] = a[i]; o[DM + i] = b[i]; o[2 * DM + i] = c[i]; }
}

// out = X + b[col]   (fp32 [NR][DM], full overwrite -> replay-safe)
__global__ __launch_bounds__(256) void preadd2_k(float* __restrict__ out,
                                                 const float* __restrict__ X,
                                                 const float* __restrict__ b) {
  int i = blockIdx.x * 256 + threadIdx.x;
  const int st = gridDim.x * 256;
  const int n4 = NR * DM / 4;
  for (; i < n4; i += st) {
    float4 x = ((const float4*)X)[i];
    float4 bb = ((const float4*)b)[i & 511];
    float4 o;
    o.x = x.x + bb.x; o.y = x.y + bb.y; o.z = x.z + bb.z; o.w = x.w + bb.w;
    ((float4*)out)[i] = o;
  }
}

// ---------------- LayerNorm: fp32 in -> bf16 out, one block per row ----------
__global__ __launch_bounds__(256) void ln_k(const float* __restrict__ X,
                                            const float* __restrict__ g,
                                            const float* __restrict__ be,
                                            u16* __restrict__ out) {
  const int row = blockIdx.x, tid = threadIdx.x;
  const float* x = X + (size_t)row * DM;
  float4 a0 = ((const float4*)x)[tid];
  float4 a1 = ((const float4*)x)[tid + 256];
  float s = a0.x + a0.y + a0.z + a0.w + a1.x + a1.y + a1.z + a1.w;
  float q = a0.x*a0.x + a0.y*a0.y + a0.z*a0.z + a0.w*a0.w
          + a1.x*a1.x + a1.y*a1.y + a1.z*a1.z + a1.w*a1.w;
  #pragma unroll
  for (int off = 32; off; off >>= 1) { s += __shfl_xor(s, off); q += __shfl_xor(q, off); }
  __shared__ float red[8];
  const int w = tid >> 6, lane = tid & 63;
  if (lane == 0) { red[w] = s; red[4 + w] = q; }
  __syncthreads();
  s = red[0] + red[1] + red[2] + red[3];
  q = red[4] + red[5] + red[6] + red[7];
  const float mean = s * (1.0f / DM);
  const float rstd = rsqrtf(q * (1.0f / DM) - mean * mean + 1e-5f);
  float4 g0 = ((const float4*)g)[tid], g1 = ((const float4*)g)[tid + 256];
  float4 b0 = ((const float4*)be)[tid], b1 = ((const float4*)be)[tid + 256];
  us4 o0, o1;
  o0.x = f2bf((a0.x - mean) * rstd * g0.x + b0.x);
  o0.y = f2bf((a0.y - mean) * rstd * g0.y + b0.y);
  o0.z = f2bf((a0.z - mean) * rstd * g0.z + b0.z);
  o0.w = f2bf((a0.w - mean) * rstd * g0.w + b0.w);
  o1.x = f2bf((a1.x - mean) * rstd * g1.x + b1.x);
  o1.y = f2bf((a1.y - mean) * rstd * g1.y + b1.y);
  o1.z = f2bf((a1.z - mean) * rstd * g1.z + b1.z);
  o1.w = f2bf((a1.w - mean) * rstd * g1.w + b1.w);
  us4* op = (us4*)(out + (size_t)row * DM);
  op[tid] = o0;
  op[tid + 256] = o1;
}

// ---------------- FAT GEMM: per-wave 128x128, 64 MFMA per 16 ds_reads -------
// BM=256, BN=512, BK=32. 512 thr = 8 waves (2M x 4N). 3 LDS slots (144 KB),
// stage slice t+2 during t, vmcnt(6) (never drain steady-state). One barrier
// pair per slice: {16 ds_read | 6 GLL | BAR | lgkm0 | setprio 64 MFMA | vmc | BAR}.
// acc[8][8] f32x4 lives in the unified VGPR/AGPR file (2 waves/SIMD -> 512 regs).
// Split-K: grid = KS*TILES, kz picks window [kz*KLEN, ...).
// MODE 1: bf16 gelu(acc+bias) -> o0    MODE 6: atomicAdd f32 (+bias iff kz==0)
template<int MODE>
__global__ __launch_bounds__(512, 1) void gemmf(
    const u16* __restrict__ A, const u16* __restrict__ W,
    const float* __restrict__ bias, float* __restrict__ o0,
    int N, int Kstr, int KLEN, int NX, int TILES) {
  constexpr int ASZ = 256 * 32;
  constexpr int BSZ = 512 * 32;
  constexpr int TSZ = ASZ + BSZ;
  extern __shared__ __align__(16) u16 lds[];
  const int tid = threadIdx.x, lane = tid & 63, w = tid >> 6;
  const int hi = lane >> 4, lo = lane & 15;
  const int bid = blockIdx.x;
  const int swz = (bid & 7) * ((int)gridDim.x >> 3) + (bid >> 3);
  const int kz = swz / TILES;
  const int tile = swz % TILES;
  const size_t brow = (size_t)(tile / NX) * 256;
  const size_t bcol = (size_t)(tile % NX) * 512;
  const int wr = (w >> 2) * 128, wc = (w & 3) * 128;
  const int kch = (hi ^ ((lo >> 1) & 3)) * 8;
  const size_t kbase = (size_t)kz * KLEN;
  // staging: per-thread pre-swizzled sources, linear LDS dsts
  const u16* aS[2]; int aD[2];
  #pragma unroll
  for (int g = 0; g < 2; ++g) {
    const int idx = g * 512 + tid;
    const int row = idx >> 2, ch = idx & 3;
    aS[g] = A + (brow + row) * (size_t)Kstr + kbase + (size_t)((ch ^ ((row >> 1) & 3)) * 8);
    aD[g] = idx * 8;
  }
  const u16* bS[4]; int bD[4];
  #pragma unroll
  for (int g = 0; g < 4; ++g) {
    const int idx = g * 512 + tid;
    const int row = idx >> 2, ch = idx & 3;
    bS[g] = W + (bcol + row) * (size_t)Kstr + kbase + (size_t)((ch ^ ((row >> 1) & 3)) * 8);
    bD[g] = idx * 8;
  }
  f32x4 acc[8][8] = {};
  const int NT = KLEN >> 5;

#define STAGEF(tt, sl) do { \
    u16* d_ = lds + (sl) * TSZ; \
    _Pragma("unroll") for (int g_ = 0; g_ < 2; ++g_) GLL(aS[g_] + (tt) * 32, d_ + aD[g_]); \
    _Pragma("unroll") for (int g_ = 0; g_ < 4; ++g_) GLL(bS[g_] + (tt) * 32, d_ + ASZ + bD[g_]); \
  } while (0)

  STAGEF(0, 0);
  STAGEF(1, 1);
  VMCN(6);           // slot0 landed; slot1's 6 in flight
  BAR();
  int slot = 0;
  for (int t = 0; t < NT; ++t) {
    const u16* Ab = lds + slot * TSZ;
    const u16* Bb = Ab + ASZ;
    bf16x8 af[8], bf[8];
    #pragma unroll
    for (int m = 0; m < 8; ++m)
      af[m] = *(const bf16x8*)(Ab + (wr + m * 16 + lo) * 32 + kch);
    #pragma unroll
    for (int n = 0; n < 8; ++n)
      bf[n] = *(const bf16x8*)(Bb + (wc + n * 16 + lo) * 32 + kch);
    if (t + 2 < NT) {
      int s2 = slot + 2; if (s2 >= 3) s2 -= 3;
      STAGEF(t + 2, s2);
    }
    BAR(); LGKM0();
    __builtin_amdgcn_s_setprio(1);
    #pragma unroll
    for (int m = 0; m < 8; ++m)
      #pragma unroll
      for (int n = 0; n < 8; ++n)
        acc[m][n] = __builtin_amdgcn_mfma_f32_16x16x32_bf16(af[m], bf[n], acc[m][n], 0, 0, 0);
    __builtin_amdgcn_s_setprio(0);
    if (t + 2 < NT) { VMCN(6); }
    else if (t + 1 < NT) { VMCN(0); }
    BAR();
    ++slot; if (slot == 3) slot = 0;
  }
#undef STAGEF
  // ---- epilogue
  #pragma unroll
  for (int m = 0; m < 8; ++m) {
    #pragma unroll
    for (int n = 0; n < 8; ++n) {
      const size_t col = bcol + wc + n * 16 + lo;
      const size_t rowb = brow + wr + m * 16 + hi * 4;
      if (MODE == 1) {
        const float bv = bias[col];
        u16* dst = (u16*)o0;
        #pragma unroll
        for (int r = 0; r < 4; ++r) {
          float v = acc[m][n][r] + bv;
          float tt = 0.7978845608028654f * (v + 0.044715f * v * v * v);
          float e2 = __expf(2.0f * tt);
          float th = 1.0f - 2.0f / (e2 + 1.0f);
          dst[(rowb + r) * (size_t)N + col] = f2bf(0.5f * v * (1.0f + th));
        }
      } else {   // MODE 6
        const float bv = (bias != nullptr && kz == 0) ? bias[col] : 0.0f;
        #pragma unroll
        for (int r = 0; r < 4; ++r)
          atomicAdd(o0 + (rowb + r) * (size_t)N + col, acc[m][n][r] + bv);
      }
    }
  }
}

// ---------------- QKV GEMM: r3/r9-proven 8-phase 256x256 core ---------------
// MODE 4 only: Q (log2e-scaled), K (scaled), V^T epilogue.
__global__ __launch_bounds__(512, 2) void gemm8p(
    const u16* __restrict__ A, const u16* __restrict__ W,
    const float* __restrict__ bias,
    void* __restrict__ o0, void* __restrict__ o1, void* __restrict__ o2,
    int N, int Kstr, int NX) {
  constexpr int ASZ = 256 * 64;
  constexpr int BSZ = 256 * 64;
  extern __shared__ __align__(16) u16 lds[];
  const int tid = threadIdx.x, lane = tid & 63, w = tid >> 6;
  const int hi = lane >> 4, lo = lane & 15;
  const int bid = blockIdx.x;
  const int swz = (bid & 7) * ((int)gridDim.x >> 3) + (bid >> 3);
  const size_t brow = (size_t)(swz / NX) * 256;
  const size_t bcol = (size_t)(swz % NX) * 256;
  const int wr = (w >> 2) * 128, wc = (w & 3) * 64;
  const int rA = tid >> 3;
  const int cA = (tid & 7) * 8;
  const int scol = cA ^ ((rA & 7) << 3);
  const int NT = DM >> 6;

#define STAGE_A(h, tt) do { \
    u16* ab_ = lds + ((tt) & 1) * (ASZ + BSZ); \
    const size_t k0_ = (size_t)(tt) * 64; \
    _Pragma("unroll") \
    for (int c_ = 0; c_ < 2; ++c_) { \
      const int row_ = (h) * 128 + c_ * 64 + rA; \
      GLL(A + (brow + row_) * (size_t)Kstr + k0_ + scol, ab_ + row_ * 64 + cA); \
    } } while (0)
#define STAGE_B(h, tt) do { \
    u16* bb_ = lds + ((tt) & 1) * (ASZ + BSZ) + ASZ; \
    const size_t k0_ = (size_t)(tt) * 64; \
    _Pragma("unroll") \
    for (int c_ = 0; c_ < 2; ++c_) { \
      const int row_ = (h) * 128 + c_ * 64 + rA; \
      GLL(W + (bcol + row_) * (size_t)Kstr + k0_ + scol, bb_ + row_ * 64 + cA); \
    } } while (0)

  const int koff[2] = { (hi * 8) ^ ((lo & 7) << 3), (32 + hi * 8) ^ ((lo & 7) << 3) };
  f32x4 acc[8][4] = {};
  bf16x8 af[4][2], b0f[2][2], b1f[2][2];

  STAGE_B(0, 0); STAGE_B(1, 0); STAGE_A(0, 0); STAGE_A(1, 0);
  STAGE_B(0, 1); STAGE_B(1, 1); STAGE_A(0, 1);
  VMCN(6);
  BAR();

  for (int t = 0; t < NT; ++t) {
    const u16* Ab = lds + (t & 1) * (ASZ + BSZ);
    const u16* Bb = Ab + ASZ;
    #pragma unroll
    for (int m = 0; m < 4; ++m)
      #pragma unroll
      for (int ks = 0; ks < 2; ++ks)
        af[m][ks] = *(const bf16x8*)(Ab + (wr + m * 16 + lo) * 64 + koff[ks]);
    #pragma unroll
    for (int n = 0; n < 2; ++n)
      #pragma unroll
      for (int ks = 0; ks < 2; ++ks)
        b0f[n][ks] = *(const bf16x8*)(Bb + (wc + n * 16 + lo) * 64 + koff[ks]);
    if (t + 1 < NT) STAGE_A(1, t + 1);
    BAR(); LGKM0();
    __builtin_amdgcn_s_setprio(1);
    #pragma unroll
    for (int m = 0; m < 4; ++m)
      #pragma unroll
      for (int n = 0; n < 2; ++n)
        #pragma unroll
        for (int ks = 0; ks < 2; ++ks)
          acc[m][n] = __builtin_amdgcn_mfma_f32_16x16x32_bf16(af[m][ks], b0f[n][ks], acc[m][n], 0, 0, 0);
    __builtin_amdgcn_s_setprio(0);
    BAR();
    #pragma unroll
    for (int n = 0; n < 2; ++n)
      #pragma unroll
      for (int ks = 0; ks < 2; ++ks)
        b1f[n][ks] = *(const bf16x8*)(Bb + (wc + (2 + n) * 16 + lo) * 64 + koff[ks]);
    BAR(); LGKM0();
    __builtin_amdgcn_s_setprio(1);
    #pragma unroll
    for (int m = 0; m < 4; ++m)
      #pragma unroll
      for (int n = 0; n < 2; ++n)
        #pragma unroll
        for (int ks = 0; ks < 2; ++ks)
          acc[m][2 + n] = __builtin_amdgcn_mfma_f32_16x16x32_bf16(af[m][ks], b1f[n][ks], acc[m][2 + n], 0, 0, 0);
    __builtin_amdgcn_s_setprio(0);
    BAR();
    #pragma unroll
    for (int m = 0; m < 4; ++m)
      #pragma unroll
      for (int ks = 0; ks < 2; ++ks)
        af[m][ks] = *(const bf16x8*)(Ab + (wr + (4 + m) * 16 + lo) * 64 + koff[ks]);
    if (t + 2 < NT) STAGE_B(0, t + 2);
    BAR(); LGKM0();
    __builtin_amdgcn_s_setprio(1);
    #pragma unroll
    for (int m = 0; m < 4; ++m)
      #pragma unroll
      for (int n = 0; n < 2; ++n)
        #pragma unroll
        for (int ks = 0; ks < 2; ++ks)
          acc[4 + m][n] = __builtin_amdgcn_mfma_f32_16x16x32_bf16(af[m][ks], b0f[n][ks], acc[4 + m][n], 0, 0, 0);
    __builtin_amdgcn_s_setprio(0);
    BAR();
    if (t + 2 < NT) { STAGE_B(1, t + 2); STAGE_A(0, t + 2); }
    BAR();
    __builtin_amdgcn_s_setprio(1);
    #pragma unroll
    for (int m = 0; m < 4; ++m)
      #pragma unroll
      for (int n = 0; n < 2; ++n)
        #pragma unroll
        for (int ks = 0; ks < 2; ++ks)
          acc[4 + m][2 + n] = __builtin_amdgcn_mfma_f32_16x16x32_bf16(af[m][ks], b1f[n][ks], acc[4 + m][2 + n], 0, 0, 0);
    __builtin_amdgcn_s_setprio(0);
    if (t + 2 < NT) { VMCN(6); }
    else if (t + 1 < NT) { VMCN(0); }
    BAR();
  }
#undef STAGE_A
#undef STAGE_B
  #pragma unroll
  for (int m = 0; m < 8; ++m) {
    #pragma unroll
    for (int n = 0; n < 4; ++n) {
      const size_t col = bcol + wc + n * 16 + lo;
      const float bv = bias[col];
      const size_t rowb = brow + wr + m * 16 + hi * 4;
      const int which = (int)(col >> 11);
      const size_t c2 = col & 2047;
      if (which == 2) {
        us4 ov;
        #pragma unroll
        for (int r = 0; r < 4; ++r) ov[r] = f2bf(acc[m][n][r] + bv);
        *(us4*)((u16*)o2 + c2 * (size_t)NR + rowb) = ov;
      } else {
        u16* dst = (u16*)(which ? o1 : o0);
        const float sc = which ? QK_SCALE : QK_SCALE_L2E;
        #pragma unroll
        for (int r = 0; r < 4; ++r)
          dst[(rowb + r) * (size_t)DM + c2] = f2bf((acc[m][n][r] + bv) * sc);
      }
    }
  }
}

// ---------------- Flash attention (causal), bf16, exp2 softmax --------------
__global__ __launch_bounds__(256) void attn_k(const u16* __restrict__ Qp,
                                              const u16* __restrict__ Kp,
                                              const u16* __restrict__ Vtp,
                                              u16* __restrict__ Op) {
  const int wid = blockIdx.x;               // 0..1023
  const int qt = 31 - (wid >> 5);           // descending work
  const int bh = wid & 31;
  const int bb = bh >> 4, h = bh & 15;
  const int tid = threadIdx.x, lane = tid & 63, w = tid >> 6;
  const int hi = lane >> 4, lo = lane & 15;
  __shared__ __align__(16) u16 Klds[KVB * 128];       // [kv][d]  swizzled
  __shared__ __align__(16) u16 Vlds[128 * KVB];       // [d][kv]  swizzled
  __shared__ __align__(16) unsigned P32[4][16 * 32];  // per-wave packed P
  const size_t baseQ = ((size_t)bb * SEQ_) * DM + (size_t)h * 128;
  const size_t baseV = (size_t)h * 128 * NR + (size_t)bb * SEQ_;
  const int q0 = qt * 64 + w * 16;
  bf16x8 qf[4];
  #pragma unroll
  for (int kq = 0; kq < 4; ++kq)
    qf[kq] = *(const bf16x8*)(Qp + baseQ + (size_t)(q0 + lo) * DM + kq * 32 + hi * 8);
  f32x4 o[8] = {};
  float mrow[4], lrow[4];
  #pragma unroll
  for (int r = 0; r < 4; ++r) { mrow[r] = -1e30f; lrow[r] = 0.0f; }
  unsigned* pw = &P32[w][0];
  const int ntile = qt + 1;
  for (int t = 0; t < ntile; ++t) {
    const int kb = t * KVB;
    __syncthreads();
    #pragma unroll
    for (int c = 0; c < 4; ++c) {
      const int el = ((w * 4 + c) * 64 + lane) * 8;
      const int row = el >> 7, col = el & 127;
      const int scol = col ^ ((row & 7) << 3);
      GLL(Kp + baseQ + (size_t)(kb + row) * DM + scol, Klds + el);
    }
    #pragma unroll
    for (int c = 0; c < 4; ++c) {
      const int el = ((w * 4 + c) * 64 + lane) * 8;
      const int row = el >> 6, col = el & 63;
      const int scol = col ^ ((row & 7) << 3);
      GLL(Vtp + baseV + (size_t)row * NR + kb + scol, Vlds + el);
    }
    __syncthreads();
    f32x4 sc[4] = {};
    #pragma unroll
    for (int kq = 0; kq < 4; ++kq) {
      #pragma unroll
      for (int kt = 0; kt < 4; ++kt) {
        const int krow = kt * 16 + lo;
        const int coff = (kq * 32 + hi * 8) ^ ((krow & 7) << 3);
        bf16x8 kf = *(const bf16x8*)(Klds + krow * 128 + coff);
        sc[kt] = __builtin_amdgcn_mfma_f32_16x16x32_bf16(qf[kq], kf, sc[kt], 0, 0, 0);
      }
    }
    if (t == ntile - 1) {
      #pragma unroll
      for (int kt = 0; kt < 4; ++kt) {
        const int kg = kb + kt * 16 + lo;
        #pragma unroll
        for (int r = 0; r < 4; ++r) {
          const int qg = q0 + hi * 4 + r;
          sc[kt][r] = (kg <= qg) ? sc[kt][r] : -1e30f;
        }
      }
    }
    float mt[4];
    #pragma unroll
    for (int r = 0; r < 4; ++r)
      mt[r] = fmaxf(fmaxf(sc[0][r], sc[1][r]), fmaxf(sc[2][r], sc[3][r]));
    #pragma unroll
    for (int r = 0; r < 4; ++r) {
      #pragma unroll
      for (int off = 1; off < 16; off <<= 1) mt[r] = fmaxf(mt[r], __shfl_xor(mt[r], off));
    }
    float scl[4], lt[4];
    #pragma unroll
    for (int r = 0; r < 4; ++r) {
      const float mn = fmaxf(mrow[r], mt[r]);
      scl[r] = exp2f(mrow[r] - mn);
      mrow[r] = mn;
      lt[r] = 0.0f;
    }
    float pv_[4][4];
    #pragma unroll
    for (int kt = 0; kt < 4; ++kt)
      #pragma unroll
      for (int r = 0; r < 4; ++r) {
        const float p = exp2f(sc[kt][r] - mrow[r]);
        pv_[kt][r] = p;
        lt[r] += p;
      }
    #pragma unroll
    for (int r = 0; r < 4; ++r) {
      #pragma unroll
      for (int off = 1; off < 16; off <<= 1) lt[r] += __shfl_xor(lt[r], off);
      lrow[r] = lrow[r] * scl[r] + lt[r];
    }
    #pragma unroll
    for (int nt = 0; nt < 8; ++nt)
      #pragma unroll
      for (int r = 0; r < 4; ++r) o[nt][r] *= scl[r];
    #pragma unroll
    for (int kt = 0; kt < 4; ++kt)
      #pragma unroll
      for (int r = 0; r < 4; ++r) {
        const float own = pv_[kt][r];
        const float pp = __shfl_xor(own, 1);
        const unsigned lo16 = (lane & 1) ? f2bf(pp) : f2bf(own);
        const unsigned hi16 = (lane & 1) ? f2bf(own) : f2bf(pp);
        const unsigned pk = lo16 | (hi16 << 16);
        if ((lane & 1) == (kt >> 1)) {
          const int row = hi * 4 + r;
          const int kp = kt * 8 + (lo >> 1);
          const int kps = (((kp >> 2) ^ (row & 7)) << 2) | (kp & 3);
          pw[row * 32 + kps] = pk;
        }
      }
    #pragma unroll
    for (int half = 0; half < 2; ++half) {
      const int ch = (half * 4 + hi) ^ (lo & 7);
      bf16x8 pf = *(const bf16x8*)((const u16*)(pw + lo * 32 + ch * 4));
      #pragma unroll
      for (int nt = 0; nt < 8; ++nt) {
        const int vrow = nt * 16 + lo;
        const int coff = (half * 32 + hi * 8) ^ ((vrow & 7) << 3);
        bf16x8 vf = *(const bf16x8*)(Vlds + vrow * 64 + coff);
        o[nt] = __builtin_amdgcn_mfma_f32_16x16x32_bf16(pf, vf, o[nt], 0, 0, 0);
      }
    }
  }
  float inv[4];
  #pragma unroll
  for (int r = 0; r < 4; ++r) inv[r] = 1.0f / lrow[r];
  #pragma unroll
  for (int nt = 0; nt < 8; ++nt)
    #pragma unroll
    for (int r = 0; r < 4; ++r) {
      const size_t row = q0 + hi * 4 + r;
      Op[baseQ + row * DM + nt * 16 + lo] = f2bf(o[nt][r] * inv[r]);
    }
}

// ---------------- launch ----------------------------------------------------
extern "C" void kernel_launch(void* const* d_in, const int* in_sizes, int n_in,
                              void* d_out, int out_size, void* d_ws, size_t ws_size,
                              hipStream_t stream) {
  (void)in_sizes; (void)n_in; (void)out_size; (void)ws_size;
  const float* X    = (const float*)d_in[0];
  const float* Wq   = (const float*)d_in[1];
  const float* bq   = (const float*)d_in[2];
  const float* Wk   = (const float*)d_in[3];
  const float* bk   = (const float*)d_in[4];
  const float* Wv   = (const float*)d_in[5];
  const float* bv   = (const float*)d_in[6];
  const float* Wo   = (const float*)d_in[7];
  const float* bo   = (const float*)d_in[8];
  const float* Win  = (const float*)d_in[9];
  const float* bin  = (const float*)d_in[10];
  const float* Wout = (const float*)d_in[11];
  const float* bout = (const float*)d_in[12];
  const float* ln1w = (const float*)d_in[13];
  const float* ln1b = (const float*)d_in[14];
  const float* ln2w = (const float*)d_in[15];
  const float* ln2b = (const float*)d_in[16];
  float* out = (float*)d_out;

  char* ws = (char*)d_ws;
  u16* wbuf  = (u16*)ws;                      // 33,554,432 B
  u16* lnb   = (u16*)(ws + 33554432);         // 16 MB
  u16* Qb    = (u16*)(ws + 50331648);
  u16* Kb    = (u16*)(ws + 67108864);
  u16* Vtb   = (u16*)(ws + 83886080);         // V transposed [d_model][b*s]
  u16* Ob    = (u16*)(ws + 100663296);
  float* bqkv = (float*)(ws + 117440512);     // 24 KB concat bias
  u16* H1    = Qb;                            // aliases Q/K/Vt/Ob (dead by MLP)

  const int LDS0 = 2 * (256 * 64 + 256 * 64) * 2;  // 131072 B
  const int LDSF = 3 * (256 * 32 + 512 * 32) * 2;  // 147456 B
  hipFuncSetAttribute((const void*)&gemm8p, hipFuncAttributeMaxDynamicSharedMemorySize, LDS0);
  hipFuncSetAttribute((const void*)&gemmf<1>, hipFuncAttributeMaxDynamicSharedMemorySize, LDSF);
  hipFuncSetAttribute((const void*)&gemmf<6>, hipFuncAttributeMaxDynamicSharedMemorySize, LDSF);

  // LN1
  ln_k<<<NR, 256, 0, stream>>>(X, ln1w, ln1b, lnb);
  // weights -> bf16 (Wq|Wk|Wv concat), bias concat
  cvt_bf16_k<<<2048, 256, 0, stream>>>(Wq, wbuf, DM * DM / 4);
  cvt_bf16_k<<<2048, 256, 0, stream>>>(Wk, wbuf + DM * DM, DM * DM / 4);
  cvt_bf16_k<<<2048, 256, 0, stream>>>(Wv, wbuf + 2 * DM * DM, DM * DM / 4);
  concat3_k<<<8, 256, 0, stream>>>(bq, bk, bv, bqkv);
  // fused QKV GEMM: N=6144, grid 16x24=384
  gemm8p<<<384, 512, LDS0, stream>>>(lnb, wbuf, bqkv, Qb, Kb, Vtb, 3 * DM, DM, 24);
  // attention
  attn_k<<<1024, 256, 0, stream>>>(Qb, Kb, Vtb, Ob);
  // X1 = X + bo (overwrite), then out += attn @ Wo^T (split-K=4 atomic, grid 256)
  cvt_bf16_k<<<2048, 256, 0, stream>>>(Wo, wbuf, DM * DM / 4);
  preadd2_k<<<2048, 256, 0, stream>>>(out, X, bo);
  gemmf<6><<<256, 512, LDSF, stream>>>(Ob, wbuf, nullptr, out,
                                       DM, DM, DM / 4, 4, 64);
  // LN2
  ln_k<<<NR, 256, 0, stream>>>(out, ln2w, ln2b, lnb);
  // H1 = gelu(ln2 @ Win^T + bin); grid 16x16=256
  cvt_bf16_k<<<2048, 256, 0, stream>>>(Win, wbuf, DFF_ * DM / 4);
  gemmf<1><<<256, 512, LDSF, stream>>>(lnb, wbuf, bin, (float*)H1,
                                       DFF_, DM, DM, 16, 256);
  // out += H1 @ Wout^T (+bout at kz==0): split-K=4 atomic, grid 256
  cvt_bf16_k<<<2048, 256, 0, stream>>>(Wout, wbuf, DM * DFF_ / 4);
  gemmf<6><<<256, 512, LDSF, stream>>>(H1, wbuf, bout, out,
                                       DM, DFF_, DFF_ / 4, 4, 64);
}

// Round 11
// 648.507 us; speedup vs baseline: 4.1266x; 4.1266x over previous
//
#include <hip/hip_runtime.h>
#include <cstdint>
#include <cstddef>

#define DM 2048
#define DFF_ 8192
#define NR 4096        // B*S rows
#define SEQ_ 2048
#define KVB 64
#define QK_SCALE 0.2973017787506803f
#define QK_SCALE_L2E 0.42891582f   // QK_SCALE * log2(e): Q pre-scaled for exp2 softmax

typedef unsigned short u16;
typedef __attribute__((ext_vector_type(8))) __bf16 bf16x8;
typedef __attribute__((ext_vector_type(8))) unsigned short us8;
typedef __attribute__((ext_vector_type(4))) unsigned short us4;
typedef __attribute__((ext_vector_type(4))) float f32x4;

static __device__ __forceinline__ u16 f2bf(float f) {
  union { float f; unsigned u; } x; x.f = f;
  unsigned r = x.u + 0x7fffu + ((x.u >> 16) & 1u);
  return (u16)(r >> 16);
}

#define GLL(srcp, dstp) __builtin_amdgcn_global_load_lds( \
    (const __attribute__((address_space(1))) void*)(srcp), \
    (__attribute__((address_space(3))) void*)(dstp), 16, 0, 0)
#define BAR() __builtin_amdgcn_s_barrier()
#define SB0() __builtin_amdgcn_sched_barrier(0)
#define LGKMN(n) do { asm volatile("s_waitcnt lgkmcnt(" #n ")" ::: "memory"); SB0(); } while (0)
#define VMCN(n)  do { asm volatile("s_waitcnt vmcnt(" #n ")" ::: "memory");  SB0(); } while (0)

// ---------------- fp32 -> bf16 conversion (vectorized, grid-stride) ----------
__global__ __launch_bounds__(256) void cvt_bf16_k(const float* __restrict__ in,
                                                  u16* __restrict__ out, int n4) {
  int i = blockIdx.x * 256 + threadIdx.x;
  int st = gridDim.x * 256;
  for (; i < n4; i += st) {
    float4 v = ((const float4*)in)[i];
    us4 o;
    o.x = f2bf(v.x); o.y = f2bf(v.y); o.z = f2bf(v.z); o.w = f2bf(v.w);
    ((us4*)out)[i] = o;
  }
}

__global__ __launch_bounds__(256) void concat3_k(const float* a, const float* b,
                                                 const float* c, float* o) {
  int i = blockIdx.x * 256 + threadIdx.x;
  if (i < DM) { o[i] = a[i]; o[DM + i] = b[i]; o[2 * DM + i] = c[i]; }
}

// ---------------- LayerNorm: fp32 in -> bf16 out, one block per row ----------
__global__ __launch_bounds__(256) void ln_k(const float* __restrict__ X,
                                            const float* __restrict__ g,
                                            const float* __restrict__ be,
                                            u16* __restrict__ out) {
  const int row = blockIdx.x, tid = threadIdx.x;
  const float* x = X + (size_t)row * DM;
  float4 a0 = ((const float4*)x)[tid];
  float4 a1 = ((const float4*)x)[tid + 256];
  float s = a0.x + a0.y + a0.z + a0.w + a1.x + a1.y + a1.z + a1.w;
  float q = a0.x*a0.x + a0.y*a0.y + a0.z*a0.z + a0.w*a0.w
          + a1.x*a1.x + a1.y*a1.y + a1.z*a1.z + a1.w*a1.w;
  #pragma unroll
  for (int off = 32; off; off >>= 1) { s += __shfl_xor(s, off); q += __shfl_xor(q, off); }
  __shared__ float red[8];
  const int w = tid >> 6, lane = tid & 63;
  if (lane == 0) { red[w] = s; red[4 + w] = q; }
  __syncthreads();
  s = red[0] + red[1] + red[2] + red[3];
  q = red[4] + red[5] + red[6] + red[7];
  const float mean = s * (1.0f / DM);
  const float rstd = rsqrtf(q * (1.0f / DM) - mean * mean + 1e-5f);
  float4 g0 = ((const float4*)g)[tid], g1 = ((const float4*)g)[tid + 256];
  float4 b0 = ((const float4*)be)[tid], b1 = ((const float4*)be)[tid + 256];
  us4 o0, o1;
  o0.x = f2bf((a0.x - mean) * rstd * g0.x + b0.x);
  o0.y = f2bf((a0.y - mean) * rstd * g0.y + b0.y);
  o0.z = f2bf((a0.z - mean) * rstd * g0.z + b0.z);
  o0.w = f2bf((a0.w - mean) * rstd * g0.w + b0.w);
  o1.x = f2bf((a1.x - mean) * rstd * g1.x + b1.x);
  o1.y = f2bf((a1.y - mean) * rstd * g1.y + b1.y);
  o1.z = f2bf((a1.z - mean) * rstd * g1.z + b1.z);
  o1.w = f2bf((a1.w - mean) * rstd * g1.w + b1.w);
  us4* op = (us4*)(out + (size_t)row * DM);
  op[tid] = o0;
  op[tid + 256] = o1;
}

// ---------------- GEMM: BM=256, BN=128, BK=64, 8 waves (4M x 2N) ------------
// r5-proven (640us config). 3 LDS buffers, stage t+2 during t (vmcnt(6)).
// Register double-buffered fragments: tile t+1's 16 ds_read_b128 issue right
// after the barrier and land under tile t's 32 MFMAs.
// Persistent per-lane global pointers (+128B/tile).
// MODE 1: bf16 gelu(acc+b)   MODE 2: f32 res+acc+b
// MODE 4: QKV fused (Q log2e-scaled, K scaled row-major; V^T us4-packed)
template<int MODE>
__global__ __launch_bounds__(512, 1) void gemmk(
    const u16* __restrict__ A, const u16* __restrict__ W,
    const float* __restrict__ bias, const float* __restrict__ res,
    void* __restrict__ o0, void* __restrict__ o1, void* __restrict__ o2,
    int N, int K, int NX) {
  constexpr int ASZ = 256 * 64;
  constexpr int BSZ = 128 * 64;
  constexpr int TSZ = ASZ + BSZ;
  extern __shared__ __align__(16) u16 lds[];
  const int tid = threadIdx.x, lane = tid & 63, w = tid >> 6;
  const int hi = lane >> 4, lo = lane & 15;
  const int bid = blockIdx.x;
  const int swz = (bid & 7) * ((int)gridDim.x >> 3) + (bid >> 3);
  const size_t brow = (size_t)(swz / NX) * 256;
  const size_t bcol = (size_t)(swz % NX) * 128;
  const int wr = (w & 3) * 64, wc = (w >> 2) * 64;
  const int rA = tid >> 3;
  const int cA = (tid & 7) * 8;
  const int scol = cA ^ ((rA & 7) << 3);
  const int NT = K >> 6;
  // persistent per-lane global pointers (advance +64 elements per staged tile)
  const u16* aP = A + (brow + rA) * (size_t)K + scol;
  const u16* wP = W + (bcol + rA) * (size_t)K + scol;
  const size_t rsA = (size_t)64 * K;     // 64-row group stride
  const int dstA = rA * 64 + cA;         // linear LDS dst (elements)
  const int k0 = (hi * 8) ^ ((lo & 7) << 3);
  const int k1 = (32 + hi * 8) ^ ((lo & 7) << 3);
  f32x4 acc[4][4] = {};
  bf16x8 Xa0[4], Xa1[4], Xb0[4], Xb1[4];
  bf16x8 Ya0[4], Ya1[4], Yb0[4], Yb1[4];
  int b2i = 2;   // buffer index for next stage (t+2)
  int bn1 = 1;   // buffer index of tile t+1 (frag prefetch)

#define STAGE6(db_) do { \
    _Pragma("unroll") for (int g_ = 0; g_ < 4; ++g_) \
      GLL(aP + g_ * rsA, (db_) + dstA + g_ * 4096); \
    _Pragma("unroll") for (int g_ = 0; g_ < 2; ++g_) \
      GLL(wP + g_ * rsA, (db_) + ASZ + dstA + g_ * 4096); \
    aP += 64; wP += 64; } while (0)

#define ITER(t_, Ca0, Ca1, Cb0, Cb1, Na0, Na1, Nb0, Nb1) do { \
    if ((t_) + 2 < NT) { STAGE6(lds + b2i * TSZ); b2i = (b2i + 1 == 3) ? 0 : b2i + 1; } \
    LGKMN(0); \
    if ((t_) + 2 < NT) { VMCN(6); } else if ((t_) + 1 < NT) { VMCN(0); } \
    BAR(); SB0(); \
    if ((t_) + 1 < NT) { \
      const u16* fb_ = lds + bn1 * TSZ; \
      _Pragma("unroll") for (int m_ = 0; m_ < 4; ++m_) { \
        Na0[m_] = *(const bf16x8*)(fb_ + (wr + m_ * 16 + lo) * 64 + k0); \
        Na1[m_] = *(const bf16x8*)(fb_ + (wr + m_ * 16 + lo) * 64 + k1); } \
      _Pragma("unroll") for (int n_ = 0; n_ < 4; ++n_) { \
        Nb0[n_] = *(const bf16x8*)(fb_ + ASZ + (wc + n_ * 16 + lo) * 64 + k0); \
        Nb1[n_] = *(const bf16x8*)(fb_ + ASZ + (wc + n_ * 16 + lo) * 64 + k1); } \
      bn1 = (bn1 + 1 == 3) ? 0 : bn1 + 1; \
    } \
    __builtin_amdgcn_s_setprio(1); \
    _Pragma("unroll") for (int m_ = 0; m_ < 4; ++m_) \
      _Pragma("unroll") for (int n_ = 0; n_ < 4; ++n_) \
        acc[m_][n_] = __builtin_amdgcn_mfma_f32_16x16x32_bf16(Ca0[m_], Cb0[n_], acc[m_][n_], 0, 0, 0); \
    _Pragma("unroll") for (int m_ = 0; m_ < 4; ++m_) \
      _Pragma("unroll") for (int n_ = 0; n_ < 4; ++n_) \
        acc[m_][n_] = __builtin_amdgcn_mfma_f32_16x16x32_bf16(Ca1[m_], Cb1[n_], acc[m_][n_], 0, 0, 0); \
    __builtin_amdgcn_s_setprio(0); \
  } while (0)

  // prologue: stage tiles 0,1; read frags(0) into X
  STAGE6(lds);
  STAGE6(lds + TSZ);
  VMCN(6);
  BAR(); SB0();
  #pragma unroll
  for (int m = 0; m < 4; ++m) {
    Xa0[m] = *(const bf16x8*)(lds + (wr + m * 16 + lo) * 64 + k0);
    Xa1[m] = *(const bf16x8*)(lds + (wr + m * 16 + lo) * 64 + k1);
  }
  #pragma unroll
  for (int n = 0; n < 4; ++n) {
    Xb0[n] = *(const bf16x8*)(lds + ASZ + (wc + n * 16 + lo) * 64 + k0);
    Xb1[n] = *(const bf16x8*)(lds + ASZ + (wc + n * 16 + lo) * 64 + k1);
  }

  for (int t = 0; t < NT; t += 2) {
    ITER(t,     Xa0, Xa1, Xb0, Xb1, Ya0, Ya1, Yb0, Yb1);
    ITER(t + 1, Ya0, Ya1, Yb0, Yb1, Xa0, Xa1, Xb0, Xb1);
  }
#undef ITER
#undef STAGE6
  // ---- epilogue
  #pragma unroll
  for (int m = 0; m < 4; ++m) {
    #pragma unroll
    for (int n = 0; n < 4; ++n) {
      const size_t col = bcol + wc + n * 16 + lo;
      const float bv = bias[col];
      const size_t rowb = brow + wr + m * 16 + hi * 4;
      if (MODE == 4) {
        const int which = (int)(col >> 11);
        const size_t c2 = col & 2047;
        if (which == 2) {
          us4 ov;
          #pragma unroll
          for (int r = 0; r < 4; ++r) ov[r] = f2bf(acc[m][n][r] + bv);
          *(us4*)((u16*)o2 + c2 * (size_t)NR + rowb) = ov;
        } else {
          u16* dst = (u16*)(which ? o1 : o0);
          const float sc = which ? QK_SCALE : QK_SCALE_L2E;
          #pragma unroll
          for (int r = 0; r < 4; ++r)
            dst[(rowb + r) * (size_t)DM + c2] = f2bf((acc[m][n][r] + bv) * sc);
        }
      } else if (MODE == 1) {
        u16* dst = (u16*)o0;
        #pragma unroll
        for (int r = 0; r < 4; ++r) {
          float v = acc[m][n][r] + bv;
          float tt = 0.7978845608028654f * (v + 0.044715f * v * v * v);
          float e2 = __expf(2.0f * tt);
          float th = 1.0f - 2.0f / (e2 + 1.0f);
          dst[(rowb + r) * (size_t)N + col] = f2bf(0.5f * v * (1.0f + th));
        }
      } else {
        float* po = (float*)o0;
        #pragma unroll
        for (int r = 0; r < 4; ++r) {
          const size_t idx = (rowb + r) * (size_t)N + col;
          po[idx] = res[idx] + acc[m][n][r] + bv;
        }
      }
    }
  }
}

// ---------------- Flash attention (causal), bf16, exp2 softmax --------------
__global__ __launch_bounds__(256) void attn_k(const u16* __restrict__ Qp,
                                              const u16* __restrict__ Kp,
                                              const u16* __restrict__ Vtp,
                                              u16* __restrict__ Op) {
  const int wid = blockIdx.x;               // 0..1023
  const int qt = 31 - (wid >> 5);           // descending work
  const int bh = wid & 31;
  const int bb = bh >> 4, h = bh & 15;
  const int tid = threadIdx.x, lane = tid & 63, w = tid >> 6;
  const int hi = lane >> 4, lo = lane & 15;
  __shared__ __align__(16) u16 Klds[KVB * 128];       // [kv][d]  swizzled
  __shared__ __align__(16) u16 Vlds[128 * KVB];       // [d][kv]  swizzled
  __shared__ __align__(16) unsigned P32[4][16 * 32];  // per-wave packed P
  const size_t baseQ = ((size_t)bb * SEQ_) * DM + (size_t)h * 128;
  const size_t baseV = (size_t)h * 128 * NR + (size_t)bb * SEQ_;
  const int q0 = qt * 64 + w * 16;
  bf16x8 qf[4];
  #pragma unroll
  for (int kq = 0; kq < 4; ++kq)
    qf[kq] = *(const bf16x8*)(Qp + baseQ + (size_t)(q0 + lo) * DM + kq * 32 + hi * 8);
  f32x4 o[8] = {};
  float mrow[4], lrow[4];
  #pragma unroll
  for (int r = 0; r < 4; ++r) { mrow[r] = -1e30f; lrow[r] = 0.0f; }
  unsigned* pw = &P32[w][0];
  const int ntile = qt + 1;
  for (int t = 0; t < ntile; ++t) {
    const int kb = t * KVB;
    __syncthreads();
    #pragma unroll
    for (int c = 0; c < 4; ++c) {
      const int el = ((w * 4 + c) * 64 + lane) * 8;
      const int row = el >> 7, col = el & 127;
      const int scol = col ^ ((row & 7) << 3);
      GLL(Kp + baseQ + (size_t)(kb + row) * DM + scol, Klds + el);
    }
    #pragma unroll
    for (int c = 0; c < 4; ++c) {
      const int el = ((w * 4 + c) * 64 + lane) * 8;
      const int row = el >> 6, col = el & 63;
      const int scol = col ^ ((row & 7) << 3);
      GLL(Vtp + baseV + (size_t)row * NR + kb + scol, Vlds + el);
    }
    __syncthreads();
    f32x4 sc[4] = {};
    #pragma unroll
    for (int kq = 0; kq < 4; ++kq) {       // kq outer: no acc dep chains
      #pragma unroll
      for (int kt = 0; kt < 4; ++kt) {
        const int krow = kt * 16 + lo;
        const int coff = (kq * 32 + hi * 8) ^ ((krow & 7) << 3);
        bf16x8 kf = *(const bf16x8*)(Klds + krow * 128 + coff);
        sc[kt] = __builtin_amdgcn_mfma_f32_16x16x32_bf16(qf[kq], kf, sc[kt], 0, 0, 0);
      }
    }
    // causal mask only on the diagonal tile
    if (t == ntile - 1) {
      #pragma unroll
      for (int kt = 0; kt < 4; ++kt) {
        const int kg = kb + kt * 16 + lo;
        #pragma unroll
        for (int r = 0; r < 4; ++r) {
          const int qg = q0 + hi * 4 + r;
          sc[kt][r] = (kg <= qg) ? sc[kt][r] : -1e30f;
        }
      }
    }
    float mt[4];
    #pragma unroll
    for (int r = 0; r < 4; ++r)
      mt[r] = fmaxf(fmaxf(sc[0][r], sc[1][r]), fmaxf(sc[2][r], sc[3][r]));
    #pragma unroll
    for (int r = 0; r < 4; ++r) {
      #pragma unroll
      for (int off = 1; off < 16; off <<= 1) mt[r] = fmaxf(mt[r], __shfl_xor(mt[r], off));
    }
    float scl[4], lt[4];
    #pragma unroll
    for (int r = 0; r < 4; ++r) {
      const float mn = fmaxf(mrow[r], mt[r]);
      scl[r] = exp2f(mrow[r] - mn);
      mrow[r] = mn;
      lt[r] = 0.0f;
    }
    float pv_[4][4];
    #pragma unroll
    for (int kt = 0; kt < 4; ++kt)
      #pragma unroll
      for (int r = 0; r < 4; ++r) {
        const float p = exp2f(sc[kt][r] - mrow[r]);
        pv_[kt][r] = p;
        lt[r] += p;
      }
    #pragma unroll
    for (int r = 0; r < 4; ++r) {
      #pragma unroll
      for (int off = 1; off < 16; off <<= 1) lt[r] += __shfl_xor(lt[r], off);
      lrow[r] = lrow[r] * scl[r] + lt[r];
    }
    #pragma unroll
    for (int nt = 0; nt < 8; ++nt)
      #pragma unroll
      for (int r = 0; r < 4; ++r) o[nt][r] *= scl[r];
    #pragma unroll
    for (int kt = 0; kt < 4; ++kt)
      #pragma unroll
      for (int r = 0; r < 4; ++r) {
        const float own = pv_[kt][r];
        const float pp = __shfl_xor(own, 1);
        const unsigned lo16 = (lane & 1) ? f2bf(pp) : f2bf(own);
        const unsigned hi16 = (lane & 1) ? f2bf(own) : f2bf(pp);
        const unsigned pk = lo16 | (hi16 << 16);
        if ((lane & 1) == (kt >> 1)) {
          const int row = hi * 4 + r;
          const int kp = kt * 8 + (lo >> 1);
          const int kps = (((kp >> 2) ^ (row & 7)) << 2) | (kp & 3);
          pw[row * 32 + kps] = pk;
        }
      }
    #pragma unroll
    for (int half = 0; half < 2; ++half) {
      const int ch = (half * 4 + hi) ^ (lo & 7);
      bf16x8 pf = *(const bf16x8*)((const u16*)(pw + lo * 32 + ch * 4));
      #pragma unroll
      for (int nt = 0; nt < 8; ++nt) {
        const int vrow = nt * 16 + lo;
        const int coff = (half * 32 + hi * 8) ^ ((vrow & 7) << 3);
        bf16x8 vf = *(const bf16x8*)(Vlds + vrow * 64 + coff);
        o[nt] = __builtin_amdgcn_mfma_f32_16x16x32_bf16(pf, vf, o[nt], 0, 0, 0);
      }
    }
  }
  float inv[4];
  #pragma unroll
  for (int r = 0; r < 4; ++r) inv[r] = 1.0f / lrow[r];
  #pragma unroll
  for (int nt = 0; nt < 8; ++nt)
    #pragma unroll
    for (int r = 0; r < 4; ++r) {
      const size_t row = q0 + hi * 4 + r;
      Op[baseQ + row * DM + nt * 16 + lo] = f2bf(o[nt][r] * inv[r]);
    }
}

// ---------------- launch ----------------------------------------------------
extern "C" void kernel_launch(void* const* d_in, const int* in_sizes, int n_in,
                              void* d_out, int out_size, void* d_ws, size_t ws_size,
                              hipStream_t stream) {
  (void)in_sizes; (void)n_in; (void)out_size; (void)ws_size;
  const float* X    = (const float*)d_in[0];
  const float* Wq   = (const float*)d_in[1];
  const float* bq   = (const float*)d_in[2];
  const float* Wk   = (const float*)d_in[3];
  const float* bk   = (const float*)d_in[4];
  const float* Wv   = (const float*)d_in[5];
  const float* bv   = (const float*)d_in[6];
  const float* Wo   = (const float*)d_in[7];
  const float* bo   = (const float*)d_in[8];
  const float* Win  = (const float*)d_in[9];
  const float* bin  = (const float*)d_in[10];
  const float* Wout = (const float*)d_in[11];
  const float* bout = (const float*)d_in[12];
  const float* ln1w = (const float*)d_in[13];
  const float* ln1b = (const float*)d_in[14];
  const float* ln2w = (const float*)d_in[15];
  const float* ln2b = (const float*)d_in[16];
  float* out = (float*)d_out;

  char* ws = (char*)d_ws;
  u16* wbuf  = (u16*)ws;                      // 33,554,432 B
  u16* lnb   = (u16*)(ws + 33554432);         // 16 MB
  u16* Qb    = (u16*)(ws + 50331648);
  u16* Kb    = (u16*)(ws + 67108864);
  u16* Vtb   = (u16*)(ws + 83886080);         // V transposed [d_model][b*s]
  u16* Ob    = (u16*)(ws + 100663296);
  float* bqkv = (float*)(ws + 117440512);     // 24 KB concat bias
  u16* H1    = Qb;                            // aliases Q/K (dead by MLP)

  const int LDSG = 3 * (256 * 64 + 128 * 64) * 2;  // 147456 B
  hipFuncSetAttribute((const void*)&gemmk<4>, hipFuncAttributeMaxDynamicSharedMemorySize, LDSG);
  hipFuncSetAttribute((const void*)&gemmk<1>, hipFuncAttributeMaxDynamicSharedMemorySize, LDSG);
  hipFuncSetAttribute((const void*)&gemmk<2>, hipFuncAttributeMaxDynamicSharedMemorySize, LDSG);

  // LN1
  ln_k<<<NR, 256, 0, stream>>>(X, ln1w, ln1b, lnb);
  // weights -> bf16 (Wq|Wk|Wv concat), bias concat
  cvt_bf16_k<<<2048, 256, 0, stream>>>(Wq, wbuf, DM * DM / 4);
  cvt_bf16_k<<<2048, 256, 0, stream>>>(Wk, wbuf + DM * DM, DM * DM / 4);
  cvt_bf16_k<<<2048, 256, 0, stream>>>(Wv, wbuf + 2 * DM * DM, DM * DM / 4);
  concat3_k<<<8, 256, 0, stream>>>(bq, bk, bv, bqkv);
  // fused QKV GEMM: N=6144, grid 16x48=768 (3 perfect rounds)
  gemmk<4><<<768, 512, LDSG, stream>>>(lnb, wbuf, bqkv, nullptr,
                                       Qb, Kb, Vtb, 3 * DM, DM, 48);
  // attention
  attn_k<<<1024, 256, 0, stream>>>(Qb, Kb, Vtb, Ob);
  // X1 = X + attn_out @ Wo^T + bo -> d_out (fp32); grid 16x16=256
  cvt_bf16_k<<<2048, 256, 0, stream>>>(Wo, wbuf, DM * DM / 4);
  gemmk<2><<<256, 512, LDSG, stream>>>(Ob, wbuf, bo, X,
                                       out, nullptr, nullptr, DM, DM, 16);
  // LN2
  ln_k<<<NR, 256, 0, stream>>>(out, ln2w, ln2b, lnb);
  // H1 = gelu(ln2 @ Win^T + bin); N=8192, grid 16x64=1024 (4 perfect rounds)
  cvt_bf16_k<<<2048, 256, 0, stream>>>(Win, wbuf, DFF_ * DM / 4);
  gemmk<1><<<1024, 512, LDSG, stream>>>(lnb, wbuf, bin, nullptr,
                                        H1, nullptr, nullptr, DFF_, DM, 64);
  // out = X1 + H1 @ Wout^T + bout; K=8192, grid 16x16=256
  cvt_bf16_k<<<2048, 256, 0, stream>>>(Wout, wbuf, DM * DFF_ / 4);
  gemmk<2><<<256, 512, LDSG, stream>>>(H1, wbuf, bout, out,
                                       out, nullptr, nullptr, DM, DFF_, 16);
}